// Round 12
// baseline (1665.266 us; speedup 1.0000x reference)
//
#include <hip/hip_runtime.h>
#include <hip/hip_bf16.h>

// Problem dims (fixed by reference). All global I/O is fp32.
#define BATCH 1024
#define DLAT  512
#define HHID  1024
#define TPTS  64
#define BD    (BATCH * DLAT)     // 524288

#define NTHR 512                 // 8 waves per block (both kernels)

// History (do not retry): W1-in-regs -> spill (r3-6). Hand-rolled asm
// signal/poll -> hang (r3). Free-running per-wave flag sync -> 2.7x regress
// (r9). r11 (512 blocks, 2/CU) failed with run-varying garbage -- consistent
// with the cooperative launch being REJECTED (grid > runtime's occupancy
// estimate) and traj never written. This round disambiguates: host queries
// occupancy for the 512-block kernel and runs it only if >=2 blocks/CU are
// granted AND the launch succeeds; otherwise falls back to the r7-proven
// 256-block kernel (1393 us).

typedef __attribute__((ext_vector_type(8))) short short8;  // 8 bf16 (4 VGPRs)
typedef __attribute__((ext_vector_type(4))) float f32x4;   // MFMA C/D frag

__device__ __forceinline__ short f2bf(float x) {
    __hip_bfloat16 h = __float2bfloat16(x);
    return __builtin_bit_cast(short, h);
}
__device__ __forceinline__ float fast_tanh(float x) {
    x = fminf(9.f, fmaxf(-9.f, x));
    const float e = __expf(2.f * x);
    return (e - 1.f) / (e + 1.f);
}

// ===========================================================================
// ============ KERNEL B: r7 verbatim — 256 blocks, 16 rg x 16 cg ============
// ===========================================================================
__device__ __forceinline__ void rg_barrier16(int* bar, int cidx, int target, int tid)
{
    __syncthreads();             // s_waitcnt vmcnt(0) lgkmcnt(0) + s_barrier
    if (tid == 0) {
        atomicAdd(&bar[cidx], 1);
        while (__hip_atomic_load(&bar[cidx], __ATOMIC_RELAXED,
                                 __HIP_MEMORY_SCOPE_AGENT) < target) {
            __builtin_amdgcn_s_sleep(2);
        }
    }
    __syncthreads();
    asm volatile("buffer_inv\n\ts_waitcnt vmcnt(0)" ::: "memory");  // L1 acquire
}

__global__ __launch_bounds__(NTHR) void ode_coop256(
    const float* __restrict__ z0, const float* __restrict__ t,
    const float* __restrict__ W1, const float* __restrict__ b1,
    const float* __restrict__ W2, const float* __restrict__ b2,
    short* __restrict__ zf, short* __restrict__ Hf,
    int* __restrict__ bar, int* __restrict__ xcnt,
    float* __restrict__ traj)
{
    __shared__ __align__(16) short W1L[4 * 16 * 64 * 8];  // 64 KB [ct][kt][lane][j]
    __shared__ __align__(16) short W2L[2 * 32 * 64 * 8];  // 64 KB [ct2][kt2][lane][j]
    __shared__ float b1L[64];
    __shared__ float b2L[32];
    __shared__ int slotS;

    const int tid  = threadIdx.x;
    const int lane = tid & 63;
    const int w    = tid >> 6;
    const int q    = lane >> 4;
    const int cl   = lane & 15;

    unsigned int xcc;
    asm("s_getreg_b32 %0, hwreg(HW_REG_XCC_ID)" : "=s"(xcc));
    xcc &= 7u;
    if (tid == 0) slotS = atomicAdd(&xcnt[xcc], 1);
    __syncthreads();
    const int slot = slotS & 31;
    const int rg   = (int)xcc * 2 + (slot >> 4);
    const int cg   = slot & 15;
    const int cidx = rg * 32;

    for (int i = tid; i < 4 * 16 * 64; i += NTHR) {
        const int ct = i >> 10, kt = (i >> 6) & 15, l = i & 63;
        const int k0 = kt * 32 + (l >> 4) * 8;
        const int n  = cg * 64 + ct * 16 + (l & 15);
        short8 v;
#pragma unroll
        for (int j = 0; j < 8; ++j) v[j] = f2bf(W1[(size_t)(k0 + j) * HHID + n]);
        *(short8*)&W1L[i * 8] = v;
    }
    for (int i = tid; i < 2 * 32 * 64; i += NTHR) {
        const int ct = i >> 11, kt = (i >> 6) & 31, l = i & 63;
        const int k0 = kt * 32 + (l >> 4) * 8;
        const int n  = cg * 32 + ct * 16 + (l & 15);
        short8 v;
#pragma unroll
        for (int j = 0; j < 8; ++j) v[j] = f2bf(W2[(size_t)(k0 + j) * DLAT + n]);
        *(short8*)&W2L[i * 8] = v;
    }
    if (tid < 64)      b1L[tid]      = b1[cg * 64 + tid];
    else if (tid < 96) b2L[tid - 64] = b2[cg * 32 + (tid - 64)];

    const int rt   = w >> 1;
    const int c0   = (w & 1) * 2;
    const int ct2b = w & 1;
    const int rowb = rg * 64 + rt * 16 + q * 4;
    const int nb   = cg * 32 + ct2b * 16 + cl;
    const int clb  = ct2b * 16 + cl;

    const size_t zbase = ((size_t)(rg * 4 + rt) * 16 + cg) * 512 +
                         (size_t)(((clb >> 3) * 16 + q * 4) * 8 + (clb & 7));
    size_t hbase[2];
#pragma unroll
    for (int c = 0; c < 2; ++c) {
        const int colc = (c0 + c) * 16 + cl;
        hbase[c] = ((size_t)(rg * 4 + rt) * 32 + cg * 2 + (colc >> 5)) * 512 +
                   (size_t)((((colc & 31) >> 3) * 16 + q * 4) * 8 + (colc & 7));
    }

    float zreg[4], kacc[4];
#pragma unroll
    for (int reg = 0; reg < 4; ++reg) {
        const float zv = z0[(size_t)(rowb + reg) * DLAT + nb];
        zreg[reg] = zv;
        traj[(size_t)(rowb + reg) * DLAT + nb] = zv;
        zf[zbase + reg * 8] = f2bf(zv);
    }

    int target = 0;
    target += 1; rg_barrier16(bar, cidx, target, tid);

    const short* zrow = zf + (size_t)(rg * 4 + rt) * 8192  + lane * 8;
    const short* hrow = Hf + (size_t)(rg * 4 + rt) * 16384 + lane * 8;
    const short* w1p  = &W1L[c0 * 8192 + lane * 8];
    const short* w2p  = &W2L[ct2b * 16384 + lane * 8];

    for (int step = 0; step < TPTS - 1; ++step) {
        const float dt = t[step + 1] - t[step];
        if (step > 0) {
#pragma unroll
            for (int reg = 0; reg < 4; ++reg)
                traj[(size_t)step * BD + (size_t)(rowb + reg) * DLAT + nb] =
                    zreg[reg];
        }
#pragma unroll
        for (int stage = 0; stage < 4; ++stage) {
            {
                f32x4 acc0 = {0.f, 0.f, 0.f, 0.f};
                f32x4 acc1 = {0.f, 0.f, 0.f, 0.f};
#pragma unroll
                for (int kt = 0; kt < 16; ++kt) {
                    const short8 a  = *(const short8*)(zrow + kt * 512);
                    const short8 bA = *(const short8*)(w1p + kt * 512);
                    const short8 bB = *(const short8*)(w1p + 8192 + kt * 512);
                    acc0 = __builtin_amdgcn_mfma_f32_16x16x32_bf16(a, bA, acc0, 0, 0, 0);
                    acc1 = __builtin_amdgcn_mfma_f32_16x16x32_bf16(a, bB, acc1, 0, 0, 0);
                }
#pragma unroll
                for (int c = 0; c < 2; ++c) {
                    const int   cloc = (c0 + c) * 16 + cl;
                    const float bb   = b1L[cloc];
                    const f32x4 av   = c ? acc1 : acc0;
#pragma unroll
                    for (int reg = 0; reg < 4; ++reg)
                        Hf[hbase[c] + reg * 8] = f2bf(fast_tanh(av[reg] + bb));
                }
            }
            target += 1; rg_barrier16(bar, cidx, target, tid);

            {
                f32x4 acce = {0.f, 0.f, 0.f, 0.f};
                f32x4 acco = {0.f, 0.f, 0.f, 0.f};
#pragma unroll
                for (int kt = 0; kt < 32; kt += 2) {
                    const short8 a0  = *(const short8*)(hrow + kt * 512);
                    const short8 a1  = *(const short8*)(hrow + kt * 512 + 512);
                    const short8 bb0 = *(const short8*)(w2p + kt * 512);
                    const short8 bb1 = *(const short8*)(w2p + kt * 512 + 512);
                    acce = __builtin_amdgcn_mfma_f32_16x16x32_bf16(a0, bb0, acce, 0, 0, 0);
                    acco = __builtin_amdgcn_mfma_f32_16x16x32_bf16(a1, bb1, acco, 0, 0, 0);
                }
                const float bb = b2L[clb];
#pragma unroll
                for (int reg = 0; reg < 4; ++reg) {
                    const float kv = acce[reg] + acco[reg] + bb;
                    float znext;
                    if (stage == 0) {
                        kacc[reg] = kv;        znext = zreg[reg] + 0.5f * dt * kv;
                    } else if (stage == 1) {
                        kacc[reg] += 2.f * kv; znext = zreg[reg] + 0.5f * dt * kv;
                    } else if (stage == 2) {
                        kacc[reg] += 2.f * kv; znext = zreg[reg] + dt * kv;
                    } else {
                        zreg[reg] += (dt * (1.f / 6.f)) * (kacc[reg] + kv);
                        znext = zreg[reg];
                    }
                    zf[zbase + reg * 8] = f2bf(znext);
                }
            }
            target += 1; rg_barrier16(bar, cidx, target, tid);
        }
    }
#pragma unroll
    for (int reg = 0; reg < 4; ++reg)
        traj[(size_t)(TPTS - 1) * BD + (size_t)(rowb + reg) * DLAT + nb] =
            zreg[reg];
}

// ===========================================================================
// ============ KERNEL A: r11 verbatim — 512 blocks, 16 rg x 32 cg ===========
// ===========================================================================
__device__ __forceinline__ void rg_barrier32(int* flg, int cg, int target, int tid)
{
    __syncthreads();
    if (tid == 0) atomicAdd(flg + cg * 4, 1);
    if (tid < 32) {
        const int* fp = flg + tid * 4;
        int v;
        do {
            v = __hip_atomic_load(fp, __ATOMIC_RELAXED,
                                  __HIP_MEMORY_SCOPE_AGENT);
            if (!__all(v >= target)) __builtin_amdgcn_s_sleep(2);
            else break;
        } while (true);
    }
    __syncthreads();
    asm volatile("buffer_inv\n\ts_waitcnt vmcnt(0)" ::: "memory");
}

__global__ __launch_bounds__(NTHR) void ode_coop512(
    const float* __restrict__ z0, const float* __restrict__ t,
    const float* __restrict__ W1, const float* __restrict__ b1,
    const float* __restrict__ W2, const float* __restrict__ b2,
    short* __restrict__ zf, short* __restrict__ Hf,
    int* __restrict__ fl, int* __restrict__ xcnt,
    float* __restrict__ traj)
{
    __shared__ __align__(16) short W1L[2 * 16 * 64 * 8];  // 32 KB [ct][kt][lane][j]
    __shared__ __align__(16) short W2L[32 * 64 * 8];      // 32 KB [kt][lane][j]
    __shared__ float Rbuf[4 * 64 * 4];                    //  4 KB split-K partials
    __shared__ float b1L[32];
    __shared__ float b2L[16];
    __shared__ int slotS;

    const int tid  = threadIdx.x;
    const int lane = tid & 63;
    const int w    = tid >> 6;
    const int q    = lane >> 4;
    const int cl   = lane & 15;

    unsigned int xcc;
    asm("s_getreg_b32 %0, hwreg(HW_REG_XCC_ID)" : "=s"(xcc));
    xcc &= 7u;
    if (tid == 0) slotS = atomicAdd(&xcnt[xcc], 1);
    __syncthreads();
    const int slot = slotS & 63;
    const int rg   = (int)xcc * 2 + (slot >> 5);
    const int cg   = slot & 31;
    int* flg = fl + rg * 128;

    for (int i = tid; i < 2 * 16 * 64; i += NTHR) {      // W1 slice [512 x 32]
        const int ct = i >> 10, kt = (i >> 6) & 15, l = i & 63;
        const int k0 = kt * 32 + (l >> 4) * 8;
        const int n  = cg * 32 + ct * 16 + (l & 15);
        short8 v;
#pragma unroll
        for (int j = 0; j < 8; ++j) v[j] = f2bf(W1[(size_t)(k0 + j) * HHID + n]);
        *(short8*)&W1L[i * 8] = v;
    }
    for (int i = tid; i < 32 * 64; i += NTHR) {          // W2 slice [1024 x 16]
        const int kt = i >> 6, l = i & 63;
        const int k0 = kt * 32 + (l >> 4) * 8;
        const int n  = cg * 16 + (l & 15);
        short8 v;
#pragma unroll
        for (int j = 0; j < 8; ++j) v[j] = f2bf(W2[(size_t)(k0 + j) * DLAT + n]);
        *(short8*)&W2L[i * 8] = v;
    }
    if (tid < 32)      b1L[tid]      = b1[cg * 32 + tid];
    else if (tid < 48) b2L[tid - 32] = b2[cg * 16 + (tid - 32)];

    const int rt    = w >> 1;
    const int ct    = w & 1;
    const int khalf = w & 1;

    const int hloc = ct * 16 + cl;
    const size_t hAbase = ((size_t)(rg * 4 + rt) * 32 + cg) * 512 +
                          (size_t)(((q * 4) | (((hloc >> 3) & 3) << 4)) * 8 + (hloc & 7));
    const int zloc = (cg & 1) * 16 + cl;
    const size_t zbase = ((size_t)(rg * 4 + rt) * 16 + (cg >> 1)) * 512 +
                         (size_t)(((q * 4) | (((zloc >> 3) & 3) << 4)) * 8 + (zloc & 7));
    const int rowb = rg * 64 + rt * 16 + q * 4;
    const int nb   = cg * 16 + cl;

    float zreg[4], kacc[4];
    if (khalf == 0) {
#pragma unroll
        for (int reg = 0; reg < 4; ++reg) {
            const float zv = z0[(size_t)(rowb + reg) * DLAT + nb];
            zreg[reg] = zv;
            traj[(size_t)(rowb + reg) * DLAT + nb] = zv;
            zf[zbase + reg * 8] = f2bf(zv);
        }
    }

    int target = 0;
    target += 1; rg_barrier32(flg, cg, target, tid);

    const short* zrow = zf + (size_t)(rg * 4 + rt) * 8192  + lane * 8;
    const short* hrow = Hf + (size_t)(rg * 4 + rt) * 16384 + lane * 8;
    const short* w1p  = &W1L[ct * 8192 + lane * 8];
    const short* w2p  = &W2L[khalf * 16 * 512 + lane * 8];

    for (int step = 0; step < TPTS - 1; ++step) {
        const float dt = t[step + 1] - t[step];
        if (step > 0 && khalf == 0) {
#pragma unroll
            for (int reg = 0; reg < 4; ++reg)
                traj[(size_t)step * BD + (size_t)(rowb + reg) * DLAT + nb] =
                    zreg[reg];
        }
#pragma unroll
        for (int stage = 0; stage < 4; ++stage) {
            {
                f32x4 acc = {0.f, 0.f, 0.f, 0.f};
#pragma unroll
                for (int kt = 0; kt < 16; ++kt) {
                    const short8 a = *(const short8*)(zrow + kt * 512);
                    const short8 b = *(const short8*)(w1p + kt * 512);
                    acc = __builtin_amdgcn_mfma_f32_16x16x32_bf16(a, b, acc, 0, 0, 0);
                }
                const float bb = b1L[hloc];
#pragma unroll
                for (int reg = 0; reg < 4; ++reg)
                    Hf[hAbase + reg * 8] = f2bf(fast_tanh(acc[reg] + bb));
            }
            target += 1; rg_barrier32(flg, cg, target, tid);

            {
                f32x4 acc = {0.f, 0.f, 0.f, 0.f};
#pragma unroll
                for (int kt = 0; kt < 16; ++kt) {
                    const short8 a = *(const short8*)(hrow + (khalf * 16 + kt) * 512);
                    const short8 b = *(const short8*)(w2p + kt * 512);
                    acc = __builtin_amdgcn_mfma_f32_16x16x32_bf16(a, b, acc, 0, 0, 0);
                }
                if (khalf == 1) {
#pragma unroll
                    for (int reg = 0; reg < 4; ++reg)
                        Rbuf[(rt * 64 + lane) * 4 + reg] = acc[reg];
                }
                __syncthreads();
                if (khalf == 0) {
                    const float bb = b2L[cl];
#pragma unroll
                    for (int reg = 0; reg < 4; ++reg) {
                        const float kv = acc[reg] +
                                         Rbuf[(rt * 64 + lane) * 4 + reg] + bb;
                        float znext;
                        if (stage == 0) {
                            kacc[reg] = kv;        znext = zreg[reg] + 0.5f * dt * kv;
                        } else if (stage == 1) {
                            kacc[reg] += 2.f * kv; znext = zreg[reg] + 0.5f * dt * kv;
                        } else if (stage == 2) {
                            kacc[reg] += 2.f * kv; znext = zreg[reg] + dt * kv;
                        } else {
                            zreg[reg] += (dt * (1.f / 6.f)) * (kacc[reg] + kv);
                            znext = zreg[reg];
                        }
                        zf[zbase + reg * 8] = f2bf(znext);
                    }
                }
            }
            target += 1; rg_barrier32(flg, cg, target, tid);
        }
    }
    if (khalf == 0) {
#pragma unroll
        for (int reg = 0; reg < 4; ++reg)
            traj[(size_t)(TPTS - 1) * BD + (size_t)(rowb + reg) * DLAT + nb] =
                zreg[reg];
    }
}

// ---------------------------------------------------------------------------
extern "C" void kernel_launch(void* const* d_in, const int* in_sizes, int n_in,
                              void* d_out, int out_size, void* d_ws, size_t ws_size,
                              hipStream_t stream)
{
    (void)in_sizes; (void)n_in; (void)out_size; (void)ws_size;

    const float* z0 = (const float*)d_in[0];
    const float* t  = (const float*)d_in[1];
    const float* W1 = (const float*)d_in[2];
    const float* b1 = (const float*)d_in[3];
    const float* W2 = (const float*)d_in[4];
    const float* b2 = (const float*)d_in[5];
    float*       traj = (float*)d_out;

    // Workspace: zf (1 MB) | Hf (2 MB) | flags (8 KB) | xcntA (32 B) | xcntB (32 B)
    short* zf    = (short*)d_ws;
    short* Hf    = (short*)((char*)d_ws + (1u << 20));
    int*   fl    = (int*)((char*)d_ws + (3u << 20));
    int*   xcntA = (int*)((char*)d_ws + (3u << 20) + 8192);
    int*   xcntB = (int*)((char*)d_ws + (3u << 20) + 8192 + 32);

    hipMemsetAsync(fl, 0, 8192 + 64, stream);

    // Occupancy probe for the 2-blocks/CU kernel (pure host query, capture-safe).
    int nb = 1;
    (void)hipOccupancyMaxActiveBlocksPerMultiprocessor(&nb, ode_coop512, NTHR, 0);

    hipError_t e = hipErrorUnknown;
    if (nb >= 2) {
        void* argsA[] = {&z0, &t, &W1, &b1, &W2, &b2, &zf, &Hf, &fl, &xcntA, &traj};
        e = hipLaunchCooperativeKernel((const void*)ode_coop512, dim3(512),
                                       dim3(NTHR), argsA, 0, stream);
    }
    if (nb < 2 || e != hipSuccess) {
        void* argsB[] = {&z0, &t, &W1, &b1, &W2, &b2, &zf, &Hf, &fl, &xcntB, &traj};
        hipLaunchCooperativeKernel((const void*)ode_coop256, dim3(256),
                                   dim3(NTHR), argsB, 0, stream);
    }
}